// Round 1
// 594.738 us; speedup vs baseline: 2.1373x; 2.1373x over previous
//
#include <hip/hip_runtime.h>

// EntityAwareLSTMLayer: B=1024, T=365, DYN=32, STATIC=27, U=256 (3U=768)
// Round 5: close the register budget for real; cut redundant LDS/cross-lane work.
//   - 256 WGs x 512 thr (8 waves, 2/SIMD, 256-reg unified budget).
//   - MROWS=4 with 4x row duplication in A (row i = batch row i&3):
//     lane (mm,qq) owns cell (batch qq, unit u) via acc reg qq -> NO shuffles,
//     cell-update VALU halves, all 256 CUs used.
//   - W_hh residual: k-chunks 0..5 in regs (36 frags=144 regs); chunks 6..7
//     streamed from a 98KB LDS tile (12 ds_read_b128/wave/step).
//   - W_ih: 6 frags = 24 regs, permanently resident (48KB LDS tile deleted).
//   - A-fragments read ONCE per step (9 b128) feeding all 6 accumulators.
//   - Register plan: 144+24 B + 24 acc + ~8 A + ~12 stream + ~30 state/addr
//     ~= 240 <= 256  -> no per-step spill reloads (the round-4 hidden cost).

typedef short short8 __attribute__((ext_vector_type(8)));
typedef float f32x4 __attribute__((ext_vector_type(4)));

#define T_STEPS 365
#define UNITS   256
#define G3      768
#define KTOT    288   // 256 (h) + 32 (x)
#define MROWS   4
#define NWGS    256
#define AP      296   // padded A row length in shorts (592 B)
#define NREG    6     // W_hh 32-k units resident in registers (ks 0..5)

__device__ __forceinline__ unsigned short f2bf(float x) {
    union { float f; unsigned u; } v; v.f = x;
    return (unsigned short)((v.u + 0x7FFFu + ((v.u >> 16) & 1u)) >> 16);
}
__device__ __forceinline__ float sigmoidf_(float x) {
    return 1.0f / (1.0f + __expf(-x));
}
__device__ __forceinline__ float tanhf_(float x) {
    return 1.0f - 2.0f / (1.0f + __expf(2.0f * x));
}
// pick element qq of a f32x4 with compile-time indices only (avoid scratch)
__device__ __forceinline__ float selq(f32x4 v, int qq) {
    const float a = (qq & 1) ? v[1] : v[0];
    const float b = (qq & 1) ? v[3] : v[2];
    return (qq & 2) ? b : a;
}
__device__ __forceinline__ f32x4 MF(short8 a, short8 b, f32x4 c) {
    return __builtin_amdgcn_mfma_f32_16x16x32_bf16(a, b, c, 0, 0, 0);
}

// Wpack[k=0..287][n=0..767] -> bf16 B-fragment layout:
//   element (k,n) at wp[((k>>3)*768 + n)*8 + (k&7)]
__global__ __launch_bounds__(256) void pack_weights(
    const float* __restrict__ w_ih, const float* __restrict__ w_hh,
    unsigned short* __restrict__ wp)
{
    int idx = blockIdx.x * 256 + threadIdx.x;
    if (idx >= KTOT * G3) return;
    int k = idx / G3, n = idx - k * G3;
    float v;
    if (k < UNITS) {
        v = w_hh[k * G3 + n];
        if ((n & 255) == k) v -= 1.0f;   // subtract eye3 tile (identity added in fp32)
    } else {
        v = w_ih[(k - UNITS) * G3 + n];
    }
    wp[(((k >> 3) * G3) + n) * 8 + (k & 7)] = f2bf(v);
}

__global__ __launch_bounds__(512, 2) void lstm_mfma(
    const float* __restrict__ x_dyn,   // [1024][365][32]
    const float* __restrict__ x_sta,   // [1024][27]
    const unsigned short* __restrict__ wp,  // packed bf16 [36][768][8]
    const float* __restrict__ w_sh,    // [27][256]
    const float* __restrict__ bias,    // [768]
    const float* __restrict__ bias_s,  // [256]
    float* __restrict__ out)           // [1024][256]
{
    __shared__ unsigned short A_s[2][16][AP];        // 18,944 B, double-buffered
    __shared__ unsigned short Bs_s[2 * 4 * G3 * 8];  // 98,304 B: W_hh chunks 24..31

    const int tid  = threadIdx.x;
    const int b0   = blockIdx.x * MROWS;
    const int lane = tid & 63;
    const int wv   = tid >> 6;          // wave 0..7, owns units wv*32..+31
    const int mm   = lane & 15;
    const int qq   = lane >> 4;

    // ---- persistent B fragments: 36 (hh) + 6 (ih) = 42 frags = 168 regs ----
    short8 bw[NREG][3][2];
    #pragma unroll
    for (int ks = 0; ks < NREG; ++ks)
        #pragma unroll
        for (int g = 0; g < 3; ++g)
            #pragma unroll
            for (int h = 0; h < 2; ++h)
                bw[ks][g][h] = *(const short8*)(wp +
                    ((size_t)(ks * 4 + qq) * G3 + g * UNITS + wv * 32 + h * 16 + mm) * 8);
    short8 bwx[3][2];
    #pragma unroll
    for (int g = 0; g < 3; ++g)
        #pragma unroll
        for (int h = 0; h < 2; ++h)
            bwx[g][h] = *(const short8*)(wp +
                ((size_t)(32 + qq) * G3 + g * UNITS + wv * 32 + h * 16 + mm) * 8);

    // ---- stage streamed W_hh chunks 24..31 (k=192..255) into LDS, once ----
    {
        const short8* src = (const short8*)(wp + (size_t)24 * G3 * 8);
        short8* dst = (short8*)Bs_s;
        for (int i = tid; i < 8 * G3; i += 512) dst[i] = src[i];
    }
    // zero both A buffers (h-region must be 0 at t=0)
    {
        int* az = (int*)A_s;
        for (int i = tid; i < 2 * 16 * AP / 2; i += 512) az[i] = 0;
    }
    __syncthreads();

    // stage x_0 into A[0] rows 0..15 (4x duplicated), prefetch x_1
    float xr = 0.0f;
    {
        const int row = tid >> 5, j = tid & 31;       // row 0..15, batch row&3
        const size_t bi = (size_t)(b0 + (row & 3)) * T_STEPS;
        A_s[0][row][UNITS + j] = f2bf(x_dyn[(bi + 0) * 32 + j]);
        xr = x_dyn[(bi + 1) * 32 + j];
    }

    // ---- cell mapping: lane (mm,qq) owns cells (batch row qq, units u0,u1) ----
    const int u0 = wv * 32 + mm;
    const int u1 = u0 + 16;

    const float bfv[2] = { bias[u0],             bias[u1] };
    const float bov[2] = { bias[UNITS + u0],     bias[UNITS + u1] };
    const float bgv[2] = { bias[2 * UNITS + u0], bias[2 * UNITS + u1] };

    float ig[2], cc[2], hp[2];
    #pragma unroll
    for (int h = 0; h < 2; ++h) {
        const int u = h ? u1 : u0;
        float s = bias_s[u];
        #pragma unroll
        for (int j = 0; j < 27; ++j)
            s += x_sta[(b0 + qq) * 27 + j] * w_sh[j * UNITS + u];
        ig[h] = sigmoidf_(s);
        cc[h] = 0.0f; hp[h] = 0.0f;
    }

    for (int t = 0; t < T_STEPS; ++t) {
        const int p = t & 1;
        __syncthreads();   // A[p] = [h_t | x_t] complete; A[p^1] free

        const unsigned short* Ap = &A_s[p][0][0];
        const int abase = mm * AP + qq * 8;

        f32x4 acf0 = {0.f,0.f,0.f,0.f}, aco0 = {0.f,0.f,0.f,0.f}, acg0 = {0.f,0.f,0.f,0.f};
        f32x4 acf1 = {0.f,0.f,0.f,0.f}, aco1 = {0.f,0.f,0.f,0.f}, acg1 = {0.f,0.f,0.f,0.f};

        // k-chunks 0..5: B in registers; each A frag read once, feeds 6 MFMAs
        #pragma unroll
        for (int ks = 0; ks < NREG; ++ks) {
            const short8 a = *(const short8*)(Ap + abase + ks * 32);
            acf0 = MF(a, bw[ks][0][0], acf0);  acf1 = MF(a, bw[ks][0][1], acf1);
            aco0 = MF(a, bw[ks][1][0], aco0);  aco1 = MF(a, bw[ks][1][1], aco1);
            acg0 = MF(a, bw[ks][2][0], acg0);  acg1 = MF(a, bw[ks][2][1], acg1);
        }
        // k-chunks 6..7: B streamed from LDS (short-lived frags)
        #pragma unroll
        for (int ks = NREG; ks < 8; ++ks) {
            const short8 a = *(const short8*)(Ap + abase + ks * 32);
            const unsigned short* bp = Bs_s +
                ((size_t)((ks - NREG) * 4 + qq) * G3 + wv * 32 + mm) * 8;
            acf0 = MF(a, *(const short8*)(bp),                      acf0);
            acf1 = MF(a, *(const short8*)(bp + 16 * 8),             acf1);
            aco0 = MF(a, *(const short8*)(bp + (UNITS) * 8),        aco0);
            aco1 = MF(a, *(const short8*)(bp + (UNITS + 16) * 8),   aco1);
            acg0 = MF(a, *(const short8*)(bp + (2 * UNITS) * 8),      acg0);
            acg1 = MF(a, *(const short8*)(bp + (2 * UNITS + 16) * 8), acg1);
        }
        // x-contribution chunk (k=256..287), B in registers
        {
            const short8 a = *(const short8*)(Ap + abase + UNITS);
            acf0 = MF(a, bwx[0][0], acf0);  acf1 = MF(a, bwx[0][1], acf1);
            aco0 = MF(a, bwx[1][0], aco0);  aco1 = MF(a, bwx[1][1], aco1);
            acg0 = MF(a, bwx[2][0], acg0);  acg1 = MF(a, bwx[2][1], acg1);
        }

        // ---- cell updates: reg qq of each acc IS this lane's cell (no shuffles) ----
        #pragma unroll
        for (int h = 0; h < 2; ++h) {
            const float h0v = hp[h];   // exact fp32 identity term of W_hh
            const float gfv = selq(h ? acf1 : acf0, qq) + bfv[h] + h0v;
            const float gov = selq(h ? aco1 : aco0, qq) + bov[h] + h0v;
            const float ggv = selq(h ? acg1 : acg0, qq) + bgv[h] + h0v;
            const float f   = sigmoidf_(gfv);
            const float o   = sigmoidf_(gov);
            const float gt  = tanhf_(ggv);
            const float cn  = f * cc[h] + ig[h] * gt;
            cc[h] = cn;
            const float hn  = o * tanhf_(cn);
            hp[h] = hn;
            const unsigned short hb = f2bf(hn);
            const int u = h ? u1 : u0;
            #pragma unroll
            for (int j = 0; j < 4; ++j)          // 4x duplicated rows
                A_s[p ^ 1][qq + 4 * j][u] = hb;
        }

        // stage x_{t+1} into A[p^1] (all 16 dup rows); prefetch x_{t+2}
        {
            const int row = tid >> 5, j = tid & 31;
            A_s[p ^ 1][row][UNITS + j] = f2bf(xr);
            if (t + 2 < T_STEPS)
                xr = x_dyn[((size_t)(b0 + (row & 3)) * T_STEPS + (t + 2)) * 32 + j];
        }
    }

    out[(size_t)(b0 + qq) * UNITS + u0] = hp[0];
    out[(size_t)(b0 + qq) * UNITS + u1] = hp[1];
}

extern "C" void kernel_launch(void* const* d_in, const int* in_sizes, int n_in,
                              void* d_out, int out_size, void* d_ws, size_t ws_size,
                              hipStream_t stream) {
    const float* x_dyn  = (const float*)d_in[0];
    const float* x_sta  = (const float*)d_in[1];
    const float* w_ih   = (const float*)d_in[2];
    const float* w_hh   = (const float*)d_in[3];
    const float* w_sh   = (const float*)d_in[4];
    const float* bias   = (const float*)d_in[5];
    const float* bias_s = (const float*)d_in[6];
    float* out = (float*)d_out;
    unsigned short* wp = (unsigned short*)d_ws;   // 288*768*2 = 442 KB scratch

    pack_weights<<<(KTOT * G3 + 255) / 256, 256, 0, stream>>>(w_ih, w_hh, wp);
    lstm_mfma<<<NWGS, 512, 0, stream>>>(x_dyn, x_sta, wp, w_sh, bias, bias_s, out);
}